// Round 5
// baseline (1135.141 us; speedup 1.0000x reference)
//
#include <hip/hip_runtime.h>
#include <hip/hip_bf16.h>

typedef __bf16 bf16x8 __attribute__((ext_vector_type(8)));
typedef float  f32x4  __attribute__((ext_vector_type(4)));

#define V_TOTAL 32768
#define NT      256
#define NV      4          // v-chunks of 64 positions per block
#define NBLK    2048       // 16 samples x 128 chunk-groups

// ---- prep: w2 fp32 -> bf16 (RNE) into workspace ----
__global__ void w2_to_bf16(const float* __restrict__ w2, __bf16* __restrict__ w2b) {
    int i = blockIdx.x * 256 + threadIdx.x;   // grid sized exactly: 8*256*256
    w2b[i] = (__bf16)w2[i];
}

__global__ __launch_bounds__(NT, 2) void fused_mlp(
    const float* __restrict__ x,  const int* __restrict__ obj,
    const float* __restrict__ w1, const float* __restrict__ b1,
    const float* __restrict__ b2, const float* __restrict__ w3,
    const float* __restrict__ b3, const __bf16* __restrict__ w2b,
    float* __restrict__ out)
{
    // h1t: [64 pos][32 chunks of 16B], chunk slot XOR-swizzled by (pos&7)
    __shared__ __align__(16) char h1t[32768];
    __shared__ float red[256];          // cross-wave L3 partials

    const int t    = threadIdx.x;
    const int lane = t & 63;
    const int wv   = t >> 6;            // wave owns M rows [wv*64, wv*64+64)
    const int llo  = lane & 15;
    const int lhi  = lane >> 4;
    const int b    = blockIdx.x >> 7;   // sample
    const int g    = blockIdx.x & 127;  // chunk group (4 chunks each)
    const int e    = __builtin_amdgcn_readfirstlane(obj[b]);

    // ---- W2 A-fragments for this wave's 64 M-rows, all K=256: 128 VGPRs ----
    const __bf16* w2e = w2b + (size_t)e * 65536;
    bf16x8 aa[8][4];
    #pragma unroll
    for (int kt = 0; kt < 8; ++kt)
        #pragma unroll
        for (int mt = 0; mt < 4; ++mt) {
            int m = wv * 64 + mt * 16 + llo;          // A[m][kt*32+lhi*8+j]
            aa[kt][mt] = *(const bf16x8*)(w2e + m * 256 + kt * 32 + lhi * 8);
        }

    const float* w1e = w1 + e * 1536;   // uniform base -> scalar loads in L1
    const float* b1e = b1 + e * 256;
    const float  b3e = b3[e];
    const int    nx  = lane & 7;

    for (int iv = 0; iv < NV; ++iv) {
        const int v0 = (g * NV + iv) * 64;

        // ---- layer 1: h1t[n][k] = relu(W1 x + b1); W1/b1 via SGPR loads ----
        {
            float xr[6];
            #pragma unroll
            for (int i = 0; i < 6; ++i)
                xr[i] = x[(size_t)(b * 6 + i) * V_TOTAL + v0 + lane];
            char* drow = h1t + lane * 512;
            #pragma unroll
            for (int q = 0; q < 8; ++q) {
                int m8 = wv * 8 + q;                  // 16B chunk (8 h-values)
                bf16x8 pack;
                #pragma unroll
                for (int j = 0; j < 8; ++j) {
                    int m = m8 * 8 + j;               // uniform -> s_load operands
                    float a = b1e[m];
                    #pragma unroll
                    for (int i2 = 0; i2 < 6; ++i2)
                        a = fmaf(w1e[m * 6 + i2], xr[i2], a);
                    pack[j] = (__bf16)fmaxf(a, 0.f);
                }
                *(bf16x8*)(drow + ((m8 ^ nx) << 4)) = pack;
            }
        }
        __syncthreads();   // h1 ready (also: prev chunk's red consumed)

        // ---- layer 2: 128 MFMA vs LDS B-frags; A from registers ----
        f32x4 acc[4][4];
        #pragma unroll
        for (int mt = 0; mt < 4; ++mt) {              // init = bias b2 (L1$-hot)
            f32x4 bv = *(const f32x4*)(b2 + e * 256 + wv * 64 + mt * 16 + lhi * 4);
            #pragma unroll
            for (int nt = 0; nt < 4; ++nt) acc[mt][nt] = bv;
        }
        #pragma unroll
        for (int kt = 0; kt < 8; ++kt) {
            bf16x8 bb[4];
            #pragma unroll
            for (int nt = 0; nt < 4; ++nt) {          // conflict-free via swizzle
                int n = nt * 16 + llo;
                bb[nt] = *(const bf16x8*)(h1t + n * 512 + (((kt * 4 + lhi) ^ (n & 7)) << 4));
            }
            #pragma unroll
            for (int mt = 0; mt < 4; ++mt)
                #pragma unroll
                for (int nt = 0; nt < 4; ++nt)
                    acc[mt][nt] = __builtin_amdgcn_mfma_f32_16x16x32_bf16(
                        aa[kt][mt], bb[nt], acc[mt][nt], 0, 0, 0);
        }

        // ---- layer 3: out[n] = sum_m w3[m]*relu(h2[m][n]) + b3 ----
        float p[4];
        #pragma unroll
        for (int nt = 0; nt < 4; ++nt) {
            float s = 0.f;
            #pragma unroll
            for (int mt = 0; mt < 4; ++mt) {
                f32x4 wf = *(const f32x4*)(w3 + e * 256 + wv * 64 + mt * 16 + lhi * 4);
                #pragma unroll
                for (int j = 0; j < 4; ++j)
                    s = fmaf(wf[j], fmaxf(acc[mt][nt][j], 0.f), s);
            }
            s += __shfl_xor(s, 16, 64);
            s += __shfl_xor(s, 32, 64);
            p[nt] = s;
        }
        if (lane < 16)
            #pragma unroll
            for (int nt = 0; nt < 4; ++nt)
                red[wv * 64 + nt * 16 + lane] = p[nt];
        __syncthreads();   // red ready AND all h1t reads done (safe to overwrite)
        if (t < 64)
            out[(size_t)b * V_TOTAL + v0 + t] =
                red[t] + red[64 + t] + red[128 + t] + red[192 + t] + b3e;
        // red is re-written only after the next chunk's post-L1 barrier -> safe
    }
}

extern "C" void kernel_launch(void* const* d_in, const int* in_sizes, int n_in,
                              void* d_out, int out_size, void* d_ws, size_t ws_size,
                              hipStream_t stream) {
    const float* x   = (const float*)d_in[0];
    const int*   obj = (const int*)d_in[1];
    const float* w1  = (const float*)d_in[2];
    const float* b1  = (const float*)d_in[3];
    const float* w2  = (const float*)d_in[4];
    const float* b2  = (const float*)d_in[5];
    const float* w3  = (const float*)d_in[6];
    const float* b3  = (const float*)d_in[7];
    float*  out = (float*)d_out;
    __bf16* w2b = (__bf16*)d_ws;   // 8*256*256 bf16 = 1 MB

    w2_to_bf16<<<2048, 256, 0, stream>>>(w2, w2b);
    fused_mlp<<<NBLK, NT, 0, stream>>>(x, obj, w1, b1, b2, w3, b3, w2b, out);
}

// Round 7
// 505.892 us; speedup vs baseline: 2.2438x; 2.2438x over previous
//
#include <hip/hip_runtime.h>
#include <hip/hip_bf16.h>

typedef __bf16 bf16x8 __attribute__((ext_vector_type(8)));
typedef float  f32x4  __attribute__((ext_vector_type(4)));

#define V_TOTAL 32768
#define NT      512        // 8 waves; wave owns 32 M-rows -> aa fits in 64 VGPRs
#define NV      4          // v-chunks of 64 positions per block
#define NBLK    2048       // 16 samples x 128 chunk-groups

// ---- prep: w2 fp32 -> bf16 (RNE) into workspace ----
__global__ void w2_to_bf16(const float* __restrict__ w2, __bf16* __restrict__ w2b) {
    int i = blockIdx.x * 256 + threadIdx.x;   // grid sized exactly: 8*256*256
    w2b[i] = (__bf16)w2[i];
}

__global__ __launch_bounds__(NT, 2) void fused_mlp(
    const float* __restrict__ x,  const int* __restrict__ obj,
    const float* __restrict__ w1, const float* __restrict__ b1,
    const float* __restrict__ b2, const float* __restrict__ w3,
    const float* __restrict__ b3, const __bf16* __restrict__ w2b,
    float* __restrict__ out)
{
    // h1t: [64 pos][32 chunks of 16B], chunk slot XOR-swizzled by (pos&7)
    __shared__ __align__(16) char h1t[32768];
    __shared__ float red[512];          // 8 waves x 64 L3 partials

    const int t    = threadIdx.x;
    const int lane = t & 63;
    const int wv   = t >> 6;            // wave owns M rows [wv*32, wv*32+32)
    const int llo  = lane & 15;
    const int lhi  = lane >> 4;
    const int b    = blockIdx.x >> 7;   // sample
    const int g    = blockIdx.x & 127;  // chunk group (4 chunks each)
    const int e    = __builtin_amdgcn_readfirstlane(obj[b]);

    // ---- W2 A-fragments: 32 rows x K=256 per wave = 64 VGPRs, loaded once ----
    const __bf16* w2e = w2b + (size_t)e * 65536;
    bf16x8 aa[8][2];
    #pragma unroll
    for (int kt = 0; kt < 8; ++kt)
        #pragma unroll
        for (int mt = 0; mt < 2; ++mt) {
            int m = wv * 32 + mt * 16 + llo;          // A[m][kt*32+lhi*8+j]
            aa[kt][mt] = *(const bf16x8*)(w2e + m * 256 + kt * 32 + lhi * 8);
        }

    const float* w1e = w1 + e * 1536;   // uniform bases -> s_load in L1 loop
    const float* b1e = b1 + e * 256;
    const float  b3e = b3[e];
    f32x4 bv[2], wf[2];                 // b2 bias + w3 row weights, hoisted
    #pragma unroll
    for (int mt = 0; mt < 2; ++mt) {
        bv[mt] = *(const f32x4*)(b2 + e * 256 + wv * 32 + mt * 16 + lhi * 4);
        wf[mt] = *(const f32x4*)(w3 + e * 256 + wv * 32 + mt * 16 + lhi * 4);
    }
    const int nx = lane & 7;

    float xr[6];                        // chunk 0 inputs
    #pragma unroll
    for (int i = 0; i < 6; ++i)
        xr[i] = x[(size_t)(b * 6 + i) * V_TOTAL + g * (NV * 64) + lane];

    for (int iv = 0; iv < NV; ++iv) {
        const int v0 = (g * NV + iv) * 64;

        // ---- layer 1: h1t[pos][k] = relu(W1 x + b1); 4 chunks of 8 per wave ----
        {
            char* drow = h1t + lane * 512;
            #pragma unroll
            for (int q = 0; q < 4; ++q) {
                int m8 = wv * 4 + q;                  // 16B chunk (8 h-values)
                bf16x8 pack;
                #pragma unroll
                for (int j = 0; j < 8; ++j) {
                    int m = m8 * 8 + j;               // uniform -> scalar operands
                    float a = b1e[m];
                    #pragma unroll
                    for (int i2 = 0; i2 < 6; ++i2)
                        a = fmaf(w1e[m * 6 + i2], xr[i2], a);
                    pack[j] = (__bf16)fmaxf(a, 0.f);
                }
                *(bf16x8*)(drow + ((m8 ^ nx) << 4)) = pack;
            }
        }
        __syncthreads();   // h1 ready

        if (iv + 1 < NV)   // prefetch next chunk's x under the MFMA phase
            #pragma unroll
            for (int i = 0; i < 6; ++i)
                xr[i] = x[(size_t)(b * 6 + i) * V_TOTAL + v0 + 64 + lane];

        // ---- layer 2: 64 MFMA/wave vs LDS B-frags; A from registers ----
        f32x4 acc[2][4];
        #pragma unroll
        for (int mt = 0; mt < 2; ++mt)
            #pragma unroll
            for (int nt = 0; nt < 4; ++nt) acc[mt][nt] = bv[mt];
        #pragma unroll
        for (int kt = 0; kt < 8; ++kt) {
            bf16x8 bb[4];
            #pragma unroll
            for (int nt = 0; nt < 4; ++nt) {          // conflict-free via swizzle
                int n = nt * 16 + llo;
                bb[nt] = *(const bf16x8*)(h1t + n * 512 + (((kt * 4 + lhi) ^ (n & 7)) << 4));
            }
            #pragma unroll
            for (int mt = 0; mt < 2; ++mt)
                #pragma unroll
                for (int nt = 0; nt < 4; ++nt)
                    acc[mt][nt] = __builtin_amdgcn_mfma_f32_16x16x32_bf16(
                        aa[kt][mt], bb[nt], acc[mt][nt], 0, 0, 0);
        }

        // ---- layer 3: out[n] = sum_m w3[m]*relu(h2[m][n]) + b3 ----
        float p[4];
        #pragma unroll
        for (int nt = 0; nt < 4; ++nt) {
            float s = 0.f;
            #pragma unroll
            for (int mt = 0; mt < 2; ++mt)
                #pragma unroll
                for (int j = 0; j < 4; ++j)
                    s = fmaf(wf[mt][j], fmaxf(acc[mt][nt][j], 0.f), s);
            s += __shfl_xor(s, 16, 64);
            s += __shfl_xor(s, 32, 64);
            p[nt] = s;                                // lanes 0-15 hold n=nt*16+lane
        }
        if (lane < 16)
            #pragma unroll
            for (int nt = 0; nt < 4; ++nt)
                red[wv * 64 + nt * 16 + lane] = p[nt];
        __syncthreads();   // red ready AND all h1t reads done (safe to overwrite)
        if (t < 64) {
            float s = b3e;
            #pragma unroll
            for (int w8 = 0; w8 < 8; ++w8) s += red[w8 * 64 + t];
            out[(size_t)b * V_TOTAL + v0 + t] = s;
        }
        // red reads finish before the next chunk's post-L1 barrier -> safe
    }
}

extern "C" void kernel_launch(void* const* d_in, const int* in_sizes, int n_in,
                              void* d_out, int out_size, void* d_ws, size_t ws_size,
                              hipStream_t stream) {
    const float* x   = (const float*)d_in[0];
    const int*   obj = (const int*)d_in[1];
    const float* w1  = (const float*)d_in[2];
    const float* b1  = (const float*)d_in[3];
    const float* w2  = (const float*)d_in[4];
    const float* b2  = (const float*)d_in[5];
    const float* w3  = (const float*)d_in[6];
    const float* b3  = (const float*)d_in[7];
    float*  out = (float*)d_out;
    __bf16* w2b = (__bf16*)d_ws;   // 8*256*256 bf16 = 1 MB

    w2_to_bf16<<<2048, 256, 0, stream>>>(w2, w2b);
    fused_mlp<<<NBLK, NT, 0, stream>>>(x, obj, w1, b1, b2, w3, b3, w2b, out);
}